// Round 9
// baseline (127.236 us; speedup 1.0000x reference)
//
#include <hip/hip_runtime.h>
#include <hip/hip_bf16.h>
#include <math.h>
#include <stdint.h>

#define L_SEQ 4096
#define NB 2
#define NH 16
#define DHEAD 64
#define DM 1024
#define DQKV 3072

typedef __bf16 bf16_t;
typedef __attribute__((ext_vector_type(8))) __bf16 bf16x8;
typedef __attribute__((ext_vector_type(4))) float f32x4;

#define GLD16(gp, lp) __builtin_amdgcn_global_load_lds(                          \
    (const __attribute__((address_space(1))) void*)(gp),                         \
    (__attribute__((address_space(3))) void*)(lp), 16, 0, 0)

template<int N> __device__ __forceinline__ void vmwait() {
    if constexpr (N == 4)      asm volatile("s_waitcnt vmcnt(4)" ::: "memory");
    else if constexpr (N == 3) asm volatile("s_waitcnt vmcnt(3)" ::: "memory");
    else if constexpr (N == 2) asm volatile("s_waitcnt vmcnt(2)" ::: "memory");
    else                       asm volatile("s_waitcnt vmcnt(0)" ::: "memory");
}

// ---------------- fused fp32->bf16 casts + conn MLP ----------------
__device__ __forceinline__ void cast8(const float* src, bf16_t* dst)
{
    const f32x4* ip = (const f32x4*)src;
    f32x4 a = ip[0], b = ip[1];
    bf16x8 o;
    o[0] = (__bf16)a[0]; o[1] = (__bf16)a[1]; o[2] = (__bf16)a[2]; o[3] = (__bf16)a[3];
    o[4] = (__bf16)b[0]; o[5] = (__bf16)b[1]; o[6] = (__bf16)b[2]; o[7] = (__bf16)b[3];
    *(bf16x8*)dst = o;
}

__device__ __forceinline__ float gelu_exact(float z)
{
    return 0.5f * z * (1.0f + erff(z * 0.7071067811865475f));
}

// blocks 0..4095: x cast; 4096..5631: wq|wk|wv; 5632..6143: wo; 6144..6159: conn
__global__ __launch_bounds__(256) void fused_cast_kernel(
    const float* __restrict__ x,  const float* __restrict__ wq,
    const float* __restrict__ wk, const float* __restrict__ wv,
    const float* __restrict__ wo,
    const float* __restrict__ cw1, const float* __restrict__ cb1,
    const float* __restrict__ cw2, const float* __restrict__ cb2,
    const float* __restrict__ cw3, const float* __restrict__ cb3,
    bf16_t* __restrict__ xb, bf16_t* __restrict__ wqkvb, bf16_t* __restrict__ wob,
    float* __restrict__ conn)
{
    const int bid = blockIdx.x;
    const int tid = threadIdx.x;
    const int nW = DM * DM / 8;
    if (bid < 4096) {
        int t = bid * 256 + tid;
        cast8(x + (size_t)t * 8, xb + (size_t)t * 8);
    } else if (bid < 5632) {
        int t = (bid - 4096) * 256 + tid;
        const float* src; int lt;
        if (t < nW)          { src = wq; lt = t; }
        else if (t < 2 * nW) { src = wk; lt = t - nW; }
        else                 { src = wv; lt = t - 2 * nW; }
        cast8(src + (size_t)lt * 8, wqkvb + (size_t)t * 8);
    } else if (bid < 6144) {
        int t = (bid - 5632) * 256 + tid;
        cast8(wo + (size_t)t * 8, wob + (size_t)t * 8);
    } else {
        // conn MLP for head h = bid - 6144 (32 active threads)
        __shared__ float h1[7][32];
        __shared__ float h2[7][32];
        const int h = bid - 6144;
        const int j = tid;
        if (j < 32) {
            for (int w = 0; w < 7; ++w) {
                float pos = (float)w / 6.0f;
                float z = pos * cw1[h * 32 + j] + cb1[h * 32 + j];
                h1[w][j] = gelu_exact(z);
            }
        }
        __syncthreads();
        if (j < 32) {
            for (int w = 0; w < 7; ++w) {
                float z = cb2[h * 32 + j];
                for (int i = 0; i < 32; ++i) z += h1[w][i] * cw2[((size_t)h * 32 + j) * 32 + i];
                h2[w][j] = gelu_exact(z);
            }
        }
        __syncthreads();
        if (j == 0) {
            float cwt[7];
            float mx = -1e30f;
            for (int w = 0; w < 7; ++w) {
                float z = cb3[h];
                for (int i = 0; i < 32; ++i) z += h2[w][i] * cw3[h * 32 + i];
                cwt[w] = z;
                mx = fmaxf(mx, z);
            }
            float Z = 0.0f;
            for (int w = 0; w < 7; ++w) { cwt[w] = expf(cwt[w] - mx); Z += cwt[w]; }
            for (int w = 0; w < 7; ++w) conn[h * 7 + w] = cwt[w] / Z;
        }
    }
}

// ---------------- 128x128 bf16 GEMM, 256 thr, BK=32, triple-buffer ----------------
// Same rhythm as the R5-proven kernel (counted vmcnt, single barrier per K-tile,
// stage-after-reads, 16 MFMA/barrier) but 4-wave blocks at 48 KB LDS
// -> 3 blocks/CU = 3 independent barrier domains (vs 2) for overlap.
// Swizzle: dest 16B slot sd holds source slot sd^((row>>1)&3); reads use
// slot^((row>>1)&3) => 2-way banks (measured 0 conflicts in R5/R8).
// Ledger (4 loads/tile/thread): prologue stage(0,1)=8 in flight; iter t:
// vmwait<4> drains tile t (t+1 stays in flight) -> s_barrier -> reads(t) ->
// stage(t+2) -> MFMA.  Tail t=NT-1: vmwait<0>.  Never a mid-loop full drain.
template<int NOUT, bool F32OUT, bool BIAS>
__global__ __launch_bounds__(256, 3) void gemm_t256(const bf16_t* __restrict__ A,
                                                    const bf16_t* __restrict__ Bw,
                                                    void* __restrict__ Cout,
                                                    const float* __restrict__ bias)
{
    constexpr int K   = 1024;
    constexpr int NT  = K / 32;            // 32
    constexpr int NTN = NOUT / 128;

    extern __shared__ char smem[];         // A: 3x8KB @0, B: 3x8KB @24576

    const int tid  = threadIdx.x;
    const int lane = tid & 63;
    const int wave = tid >> 6;             // 4 waves: 2M x 2N
    const int wm   = (wave >> 1) * 64;
    const int wn   = (wave & 1) * 64;

    // XCD-aware bijective swizzle, bn-fastest (nwg % 8 == 0)
    const int nwg = gridDim.x;
    int id = blockIdx.x;
    id = (id & 7) * (nwg >> 3) + (id >> 3);
    const int bm = (id / NTN) * 128;
    const int bn = (id % NTN) * 128;

    // staging: thread covers row tid>>2 (0..63) of each 64-row chunk, slot tid&3;
    // source pre-swizzled: elem = ((tid&3) ^ ((row>>1)&3)) * 8
    const int srow = tid >> 2;
    const int scol = ((tid & 3) ^ ((tid >> 3) & 3)) * 8;
    const bf16_t* Ag = A  + (size_t)(bm + srow) * K + scol;
    const bf16_t* Bg = Bw + (size_t)(bn + srow) * K + scol;

    auto stage = [&](int kt) {
        char* la = smem + (kt % 3) * 8192 + tid * 16;
#pragma unroll
        for (int bl = 0; bl < 2; ++bl)
            GLD16(Ag + (size_t)(bl * 64) * K + kt * 32, la + bl * 4096);
        char* lb = smem + 24576 + (kt % 3) * 8192 + tid * 16;
#pragma unroll
        for (int bl = 0; bl < 2; ++bl)
            GLD16(Bg + (size_t)(bl * 64) * K + kt * 32, lb + bl * 4096);
    };

    f32x4 acc[4][4] = {};

    stage(0); stage(1);

    // swizzled read offsets: row bits 1-2 come from lane bits 1-2
    int aoff[4], boff[4];
    const int slot = (((lane >> 4) ^ ((lane >> 1) & 3)) * 16);
#pragma unroll
    for (int m = 0; m < 4; ++m) aoff[m] = (wm + m * 16 + (lane & 15)) * 64 + slot;
#pragma unroll
    for (int n = 0; n < 4; ++n) boff[n] = (wn + n * 16 + (lane & 15)) * 64 + slot;

    for (int t = 0; t < NT; ++t) {
        if (t < NT - 1) vmwait<4>(); else vmwait<0>();
        __builtin_amdgcn_s_barrier();
        asm volatile("" ::: "memory");

        const char* Ab = smem + (t % 3) * 8192;
        const char* Bb = smem + 24576 + (t % 3) * 8192;

        bf16x8 af[4], bfr[4];
#pragma unroll
        for (int m = 0; m < 4; ++m) af[m]  = *(const bf16x8*)(Ab + aoff[m]);
#pragma unroll
        for (int n = 0; n < 4; ++n) bfr[n] = *(const bf16x8*)(Bb + boff[n]);

        if (t + 2 < NT) {
            __builtin_amdgcn_sched_barrier(0);   // reads issue before stage
            stage(t + 2);
        }

        __builtin_amdgcn_s_setprio(1);
#pragma unroll
        for (int m = 0; m < 4; ++m)
#pragma unroll
            for (int n = 0; n < 4; ++n)
                acc[m][n] = __builtin_amdgcn_mfma_f32_16x16x32_bf16(af[m], bfr[n], acc[m][n], 0, 0, 0);
        __builtin_amdgcn_s_setprio(0);
    }

    // epilogue: C/D frag layout col=lane&15, row=(lane>>4)*4+reg
    const int r0 = (lane >> 4) * 4;
    const int c0 = lane & 15;
#pragma unroll
    for (int m = 0; m < 4; ++m) {
#pragma unroll
        for (int n = 0; n < 4; ++n) {
            const int col = bn + wn + n * 16 + c0;
            float bv = BIAS ? bias[col] : 0.0f;
#pragma unroll
            for (int r = 0; r < 4; ++r) {
                const int row = bm + wm + m * 16 + r0 + r;
                float v = acc[m][n][r] + bv;
                if (F32OUT) ((float*)Cout)[(size_t)row * NOUT + col] = v;
                else        ((bf16_t*)Cout)[(size_t)row * NOUT + col] = (__bf16)v;
            }
        }
    }
}

// ---------------- windowed attention, LDS-staged K/V (R8-proven) ----------------
#define LCH 128
#define KROWS (LCH + 7)
#define RSTR 72

__global__ __launch_bounds__(256) void attn_win_kernel(const bf16_t* __restrict__ QKV,
                                                       const float* __restrict__ conn,
                                                       bf16_t* __restrict__ AO)
{
    __shared__ bf16_t Kl[KROWS * RSTR];
    __shared__ bf16_t Vl[KROWS * RSTR];

    const int tid = threadIdx.x;
    const int blk = blockIdx.x;
    const int lc  = blk & 31;
    const int h   = (blk >> 5) & (NH - 1);
    const int b   = blk >> 9;
    const int l0  = lc * LCH;
    const size_t baseK = (size_t)b * L_SEQ * DQKV + DM + h * DHEAD;
    const size_t baseV = baseK + DM;

#pragma unroll
    for (int it = 0; it < 5; ++it) {
        const int idx = it * 256 + tid;
        if (idx >= KROWS * 8) break;
        const int row = idx >> 3, c = idx & 7;
        const int l = l0 - 3 + row;
        bf16x8 kv = {}, vv = {};
        if ((unsigned)l < L_SEQ) {
            kv = *(const bf16x8*)(QKV + baseK + (size_t)l * DQKV + c * 8);
            vv = *(const bf16x8*)(QKV + baseV + (size_t)l * DQKV + c * 8);
        }
        *(bf16x8*)(Kl + row * RSTR + c * 8) = kv;
        *(bf16x8*)(Vl + row * RSTR + c * 8) = vv;
    }
    __syncthreads();

    const int ll = tid >> 3;
    const int c  = tid & 7;

#pragma unroll
    for (int q = 0; q < LCH / 32; ++q) {
        const int lrow = ll + q * 32;
        const int l    = l0 + lrow;
        const size_t row = (size_t)b * L_SEQ + l;

        const bf16x8 qv = *(const bf16x8*)(QKV + row * DQKV + h * DHEAD + c * 8);

        float s[7];
#pragma unroll
        for (int o = 0; o < 7; ++o) {
            const bf16x8 kv = *(const bf16x8*)(Kl + (lrow + o) * RSTR + c * 8);
            float d = 0.0f;
#pragma unroll
            for (int j = 0; j < 8; ++j) d += (float)qv[j] * (float)kv[j];
            s[o] = d;
        }
#pragma unroll
        for (int m = 1; m < 8; m <<= 1) {
#pragma unroll
            for (int o = 0; o < 7; ++o) s[o] += __shfl_xor(s[o], m, 64);
        }

        float mx = -1e30f;
#pragma unroll
        for (int o = 0; o < 7; ++o) { s[o] *= 0.125f; mx = fmaxf(mx, s[o]); }
        float e[7], Z = 0.0f;
#pragma unroll
        for (int o = 0; o < 7; ++o) { e[o] = expf(s[o] - mx); Z += e[o]; }

        float fw[7], fs = 0.0f;
#pragma unroll
        for (int o = 0; o < 7; ++o) { fw[o] = e[o] * conn[h * 7 + o]; fs += fw[o]; }
        const float inv = 1.0f / (fs + 1e-9f * Z);

        float outv[8] = {};
#pragma unroll
        for (int o = 0; o < 7; ++o) {
            const float w = fw[o] * inv;
            const bf16x8 vv = *(const bf16x8*)(Vl + (lrow + o) * RSTR + c * 8);
#pragma unroll
            for (int j = 0; j < 8; ++j) outv[j] += w * (float)vv[j];
        }

        bf16x8 ov;
#pragma unroll
        for (int j = 0; j < 8; ++j) ov[j] = (__bf16)outv[j];
        *(bf16x8*)(AO + row * DM + h * DHEAD + c * 8) = ov;
    }
}

// ---------------- launch ----------------
extern "C" void kernel_launch(void* const* d_in, const int* in_sizes, int n_in,
                              void* d_out, int out_size, void* d_ws, size_t ws_size,
                              hipStream_t stream)
{
    const float* x   = (const float*)d_in[0];
    const float* wq  = (const float*)d_in[1];
    const float* wk  = (const float*)d_in[2];
    const float* wv  = (const float*)d_in[3];
    const float* wo  = (const float*)d_in[4];
    const float* bo  = (const float*)d_in[5];
    const float* cw1 = (const float*)d_in[6];
    const float* cb1 = (const float*)d_in[7];
    const float* cw2 = (const float*)d_in[8];
    const float* cb2 = (const float*)d_in[9];
    const float* cw3 = (const float*)d_in[10];
    const float* cb3 = (const float*)d_in[11];
    float* out = (float*)d_out;

    char* ws = (char*)d_ws;
    const size_t MB = 1024 * 1024;
    bf16_t* xb    = (bf16_t*)(ws);             // 16 MB; reused as attention output
    bf16_t* wqkvb = (bf16_t*)(ws + 16 * MB);   // 6 MB   [3072][1024]
    bf16_t* wob   = (bf16_t*)(ws + 22 * MB);   // 2 MB
    bf16_t* QKV   = (bf16_t*)(ws + 24 * MB);   // 48 MB  [8192][3072]
    float*  conn  = (float*)(ws + 72 * MB);    // 448 B

    (void)hipFuncSetAttribute((const void*)gemm_t256<DQKV, false, false>,
                              hipFuncAttributeMaxDynamicSharedMemorySize, 49152);
    (void)hipFuncSetAttribute((const void*)gemm_t256<DM, true, true>,
                              hipFuncAttributeMaxDynamicSharedMemorySize, 49152);

    // casts + conn in one launch
    fused_cast_kernel<<<6160, 256, 0, stream>>>(x, wq, wk, wv, wo,
                                                cw1, cb1, cw2, cb2, cw3, cb3,
                                                xb, wqkvb, wob, conn);

    // QKV: 64 x 24 = 1536 blocks (3 blocks/CU resident)
    gemm_t256<DQKV, false, false><<<1536, 256, 49152, stream>>>(xb, wqkvb, QKV, nullptr);

    // attention: 1024 blocks, LDS-staged K/V
    attn_win_kernel<<<NB * NH * (L_SEQ / LCH), 256, 0, stream>>>(QKV, conn, xb);

    // out-proj: 64 x 8 = 512 blocks
    gemm_t256<DM, true, true><<<512, 256, 49152, stream>>>(xb, wob, out, bo);
}

// Round 10
// 124.834 us; speedup vs baseline: 1.0192x; 1.0192x over previous
//
#include <hip/hip_runtime.h>
#include <hip/hip_bf16.h>
#include <math.h>
#include <stdint.h>

#define L_SEQ 4096
#define NB 2
#define NH 16
#define DHEAD 64
#define DM 1024
#define DQKV 3072

typedef __bf16 bf16_t;
typedef __attribute__((ext_vector_type(8))) __bf16 bf16x8;
typedef __attribute__((ext_vector_type(4))) float f32x4;
typedef __attribute__((ext_vector_type(16))) float f32x16;

#define GLD16(gp, lp) __builtin_amdgcn_global_load_lds(                          \
    (const __attribute__((address_space(1))) void*)(gp),                         \
    (__attribute__((address_space(3))) void*)(lp), 16, 0, 0)

template<int N> __device__ __forceinline__ void vmwait() {
    if constexpr (N == 3)      asm volatile("s_waitcnt vmcnt(3)" ::: "memory");
    else if constexpr (N == 2) asm volatile("s_waitcnt vmcnt(2)" ::: "memory");
    else                       asm volatile("s_waitcnt vmcnt(0)" ::: "memory");
}

// ---------------- fused fp32->bf16 casts + conn MLP ----------------
__device__ __forceinline__ void cast8(const float* src, bf16_t* dst)
{
    const f32x4* ip = (const f32x4*)src;
    f32x4 a = ip[0], b = ip[1];
    bf16x8 o;
    o[0] = (__bf16)a[0]; o[1] = (__bf16)a[1]; o[2] = (__bf16)a[2]; o[3] = (__bf16)a[3];
    o[4] = (__bf16)b[0]; o[5] = (__bf16)b[1]; o[6] = (__bf16)b[2]; o[7] = (__bf16)b[3];
    *(bf16x8*)dst = o;
}

__device__ __forceinline__ float gelu_exact(float z)
{
    return 0.5f * z * (1.0f + erff(z * 0.7071067811865475f));
}

// blocks 0..4095: x; 4096..5631: wq|wk|wv; 5632..6143: wo; 6144..6159: conn
__global__ __launch_bounds__(256) void fused_cast_kernel(
    const float* __restrict__ x,  const float* __restrict__ wq,
    const float* __restrict__ wk, const float* __restrict__ wv,
    const float* __restrict__ wo,
    const float* __restrict__ cw1, const float* __restrict__ cb1,
    const float* __restrict__ cw2, const float* __restrict__ cb2,
    const float* __restrict__ cw3, const float* __restrict__ cb3,
    bf16_t* __restrict__ xb, bf16_t* __restrict__ wqkvb, bf16_t* __restrict__ wob,
    float* __restrict__ conn)
{
    const int bid = blockIdx.x;
    const int tid = threadIdx.x;
    const int nW = DM * DM / 8;
    if (bid < 4096) {
        int t = bid * 256 + tid;
        cast8(x + (size_t)t * 8, xb + (size_t)t * 8);
    } else if (bid < 5632) {
        int t = (bid - 4096) * 256 + tid;
        const float* src; int lt;
        if (t < nW)          { src = wq; lt = t; }
        else if (t < 2 * nW) { src = wk; lt = t - nW; }
        else                 { src = wv; lt = t - 2 * nW; }
        cast8(src + (size_t)lt * 8, wqkvb + (size_t)t * 8);
    } else if (bid < 6144) {
        int t = (bid - 5632) * 256 + tid;
        cast8(wo + (size_t)t * 8, wob + (size_t)t * 8);
    } else {
        __shared__ float h1[7][32];
        __shared__ float h2[7][32];
        const int h = bid - 6144;
        const int j = tid;
        if (j < 32) {
            for (int w = 0; w < 7; ++w) {
                float pos = (float)w / 6.0f;
                float z = pos * cw1[h * 32 + j] + cb1[h * 32 + j];
                h1[w][j] = gelu_exact(z);
            }
        }
        __syncthreads();
        if (j < 32) {
            for (int w = 0; w < 7; ++w) {
                float z = cb2[h * 32 + j];
                for (int i = 0; i < 32; ++i) z += h1[w][i] * cw2[((size_t)h * 32 + j) * 32 + i];
                h2[w][j] = gelu_exact(z);
            }
        }
        __syncthreads();
        if (j == 0) {
            float cwt[7];
            float mx = -1e30f;
            for (int w = 0; w < 7; ++w) {
                float z = cb3[h];
                for (int i = 0; i < 32; ++i) z += h2[w][i] * cw3[h * 32 + i];
                cwt[w] = z;
                mx = fmaxf(mx, z);
            }
            float Z = 0.0f;
            for (int w = 0; w < 7; ++w) { cwt[w] = expf(cwt[w] - mx); Z += cwt[w]; }
            for (int w = 0; w < 7; ++w) conn[h * 7 + w] = cwt[w] / Z;
        }
    }
}

// ---------------- BMxBN bf16 GEMM, BK=32, triple-buffer, MFMA 32x32x16 ----------------
// Identical pipeline to the R8-proven kernel (counted vmcnt, single barrier per
// K-tile, stage-after-reads, triple buffer, XOR slot swizzle, XCD swizzle) —
// ONLY the MFMA shape changes: 8x mfma_f32_32x32x16_bf16 per wave per K-tile
// (was 16x 16x16x32).  A/B frag: row=lane&31, k0=(lane>>5)*8 within the kk
// half; C/D: col=lane&31, row=(reg&3)+8*(reg>>2)+4*(lane>>5) [m74/m101].
// 512 thr = 8 waves as 4M x 2N; wave tile (BM/4) x (BN/2); MI=BM/128, NJ=BN/64.
template<int BM, int BN, int NOUT, bool F32OUT, bool BIAS>
__global__ __launch_bounds__(512, 4) void gemm_fp(const bf16_t* __restrict__ A,
                                                  const bf16_t* __restrict__ Bw,
                                                  void* __restrict__ Cout,
                                                  const float* __restrict__ bias)
{
    constexpr int K   = 1024;
    constexpr int NT  = K / 32;
    constexpr int MI  = BM / 128;          // 32-row blocks per wave
    constexpr int NJ  = BN / 64;           // 32-col blocks per wave
    constexpr int LA  = BM / 128;
    constexpr int LB  = BN / 128;
    constexpr int L   = LA + LB;
    constexpr int ASZ = BM * 64;
    constexpr int BSZ = BN * 64;
    constexpr int NTN = NOUT / BN;

    extern __shared__ char smem[];

    const int tid  = threadIdx.x;
    const int lane = tid & 63;
    const int wave = tid >> 6;
    const int wm   = (wave >> 1) * (BM / 4);
    const int wn   = (wave & 1) * (BN / 2);

    const int nwg = gridDim.x;
    int id = blockIdx.x;
    id = (id & 7) * (nwg >> 3) + (id >> 3);
    const int bm = (id / NTN) * BM;
    const int bn = (id % NTN) * BN;

    const int scol = (((tid & 3) ^ ((tid >> 3) & 3)) * 8);
    const int srow = tid >> 2;
    const bf16_t* Ag = A  + (size_t)(bm + srow) * K + scol;
    const bf16_t* Bg = Bw + (size_t)(bn + srow) * K + scol;

    auto stage = [&](int kt) {
        char* la = smem + (kt % 3) * ASZ + tid * 16;
#pragma unroll
        for (int bl = 0; bl < LA; ++bl)
            GLD16(Ag + (size_t)(bl * 128) * K + kt * 32, la + bl * 8192);
        char* lb = smem + 3 * ASZ + (kt % 3) * BSZ + tid * 16;
#pragma unroll
        for (int bl = 0; bl < LB; ++bl)
            GLD16(Bg + (size_t)(bl * 128) * K + kt * 32, lb + bl * 8192);
    };

    f32x16 acc[MI][NJ] = {};

    stage(0); stage(1);

    // frag read offsets: row = base + (lane&31), 16B slot = (kk*2 + (lane>>5)) ^ ((lane>>1)&3)
    // (row base is a multiple of 32 so (row>>1)&3 == ((lane>>1)&3))
    const int fx = (lane >> 1) & 3;
    int aoff[MI][2], boff[NJ][2];
#pragma unroll
    for (int m = 0; m < MI; ++m)
#pragma unroll
        for (int kk = 0; kk < 2; ++kk)
            aoff[m][kk] = (wm + m * 32 + (lane & 31)) * 64
                        + (((kk * 2 + (lane >> 5)) ^ fx) * 16);
#pragma unroll
    for (int n = 0; n < NJ; ++n)
#pragma unroll
        for (int kk = 0; kk < 2; ++kk)
            boff[n][kk] = (wn + n * 32 + (lane & 31)) * 64
                        + (((kk * 2 + (lane >> 5)) ^ fx) * 16);

    for (int t = 0; t < NT; ++t) {
        if (t < NT - 1) vmwait<L>(); else vmwait<0>();
        __builtin_amdgcn_s_barrier();
        asm volatile("" ::: "memory");

        const char* Ab = smem + (t % 3) * ASZ;
        const char* Bb = smem + 3 * ASZ + (t % 3) * BSZ;

        bf16x8 af[MI][2], bfr[NJ][2];
#pragma unroll
        for (int m = 0; m < MI; ++m)
#pragma unroll
            for (int kk = 0; kk < 2; ++kk) af[m][kk]  = *(const bf16x8*)(Ab + aoff[m][kk]);
#pragma unroll
        for (int n = 0; n < NJ; ++n)
#pragma unroll
            for (int kk = 0; kk < 2; ++kk) bfr[n][kk] = *(const bf16x8*)(Bb + boff[n][kk]);

        if (t + 2 < NT) {
            __builtin_amdgcn_sched_barrier(0);   // reads issue before stage
            stage(t + 2);
        }

        __builtin_amdgcn_s_setprio(1);
#pragma unroll
        for (int m = 0; m < MI; ++m)
#pragma unroll
            for (int n = 0; n < NJ; ++n)
#pragma unroll
                for (int kk = 0; kk < 2; ++kk)
                    acc[m][n] = __builtin_amdgcn_mfma_f32_32x32x16_bf16(
                        af[m][kk], bfr[n][kk], acc[m][n], 0, 0, 0);
        __builtin_amdgcn_s_setprio(0);
    }

    // epilogue: C/D col=lane&31, row=(reg&3)+8*(reg>>2)+4*(lane>>5)  [m74/m101]
    const int c0 = lane & 31;
    const int rhi = (lane >> 5) * 4;
#pragma unroll
    for (int m = 0; m < MI; ++m) {
#pragma unroll
        for (int n = 0; n < NJ; ++n) {
            const int col = bn + wn + n * 32 + c0;
            float bv = BIAS ? bias[col] : 0.0f;
#pragma unroll
            for (int r = 0; r < 16; ++r) {
                const int row = bm + wm + m * 32 + (r & 3) + 8 * (r >> 2) + rhi;
                float v = acc[m][n][r] + bv;
                if (F32OUT) ((float*)Cout)[(size_t)row * NOUT + col] = v;
                else        ((bf16_t*)Cout)[(size_t)row * NOUT + col] = (__bf16)v;
            }
        }
    }
}

// ---------------- windowed attention, LDS-staged K/V (R8-proven) ----------------
#define LCH 128
#define KROWS (LCH + 7)
#define RSTR 72

__global__ __launch_bounds__(256) void attn_win_kernel(const bf16_t* __restrict__ QKV,
                                                       const float* __restrict__ conn,
                                                       bf16_t* __restrict__ AO)
{
    __shared__ bf16_t Kl[KROWS * RSTR];
    __shared__ bf16_t Vl[KROWS * RSTR];

    const int tid = threadIdx.x;
    const int blk = blockIdx.x;
    const int lc  = blk & 31;
    const int h   = (blk >> 5) & (NH - 1);
    const int b   = blk >> 9;
    const int l0  = lc * LCH;
    const size_t baseK = (size_t)b * L_SEQ * DQKV + DM + h * DHEAD;
    const size_t baseV = baseK + DM;

#pragma unroll
    for (int it = 0; it < 5; ++it) {
        const int idx = it * 256 + tid;
        if (idx >= KROWS * 8) break;
        const int row = idx >> 3, c = idx & 7;
        const int l = l0 - 3 + row;
        bf16x8 kv = {}, vv = {};
        if ((unsigned)l < L_SEQ) {
            kv = *(const bf16x8*)(QKV + baseK + (size_t)l * DQKV + c * 8);
            vv = *(const bf16x8*)(QKV + baseV + (size_t)l * DQKV + c * 8);
        }
        *(bf16x8*)(Kl + row * RSTR + c * 8) = kv;
        *(bf16x8*)(Vl + row * RSTR + c * 8) = vv;
    }
    __syncthreads();

    const int ll = tid >> 3;
    const int c  = tid & 7;

#pragma unroll
    for (int q = 0; q < LCH / 32; ++q) {
        const int lrow = ll + q * 32;
        const int l    = l0 + lrow;
        const size_t row = (size_t)b * L_SEQ + l;

        const bf16x8 qv = *(const bf16x8*)(QKV + row * DQKV + h * DHEAD + c * 8);

        float s[7];
#pragma unroll
        for (int o = 0; o < 7; ++o) {
            const bf16x8 kv = *(const bf16x8*)(Kl + (lrow + o) * RSTR + c * 8);
            float d = 0.0f;
#pragma unroll
            for (int j = 0; j < 8; ++j) d += (float)qv[j] * (float)kv[j];
            s[o] = d;
        }
#pragma unroll
        for (int m = 1; m < 8; m <<= 1) {
#pragma unroll
            for (int o = 0; o < 7; ++o) s[o] += __shfl_xor(s[o], m, 64);
        }

        float mx = -1e30f;
#pragma unroll
        for (int o = 0; o < 7; ++o) { s[o] *= 0.125f; mx = fmaxf(mx, s[o]); }
        float e[7], Z = 0.0f;
#pragma unroll
        for (int o = 0; o < 7; ++o) { e[o] = expf(s[o] - mx); Z += e[o]; }

        float fw[7], fs = 0.0f;
#pragma unroll
        for (int o = 0; o < 7; ++o) { fw[o] = e[o] * conn[h * 7 + o]; fs += fw[o]; }
        const float inv = 1.0f / (fs + 1e-9f * Z);

        float outv[8] = {};
#pragma unroll
        for (int o = 0; o < 7; ++o) {
            const float w = fw[o] * inv;
            const bf16x8 vv = *(const bf16x8*)(Vl + (lrow + o) * RSTR + c * 8);
#pragma unroll
            for (int j = 0; j < 8; ++j) outv[j] += w * (float)vv[j];
        }

        bf16x8 ov;
#pragma unroll
        for (int j = 0; j < 8; ++j) ov[j] = (__bf16)outv[j];
        *(bf16x8*)(AO + row * DM + h * DHEAD + c * 8) = ov;
    }
}

// ---------------- launch ----------------
extern "C" void kernel_launch(void* const* d_in, const int* in_sizes, int n_in,
                              void* d_out, int out_size, void* d_ws, size_t ws_size,
                              hipStream_t stream)
{
    const float* x   = (const float*)d_in[0];
    const float* wq  = (const float*)d_in[1];
    const float* wk  = (const float*)d_in[2];
    const float* wv  = (const float*)d_in[3];
    const float* wo  = (const float*)d_in[4];
    const float* bo  = (const float*)d_in[5];
    const float* cw1 = (const float*)d_in[6];
    const float* cb1 = (const float*)d_in[7];
    const float* cw2 = (const float*)d_in[8];
    const float* cb2 = (const float*)d_in[9];
    const float* cw3 = (const float*)d_in[10];
    const float* cb3 = (const float*)d_in[11];
    float* out = (float*)d_out;

    char* ws = (char*)d_ws;
    const size_t MB = 1024 * 1024;
    bf16_t* xb    = (bf16_t*)(ws);             // 16 MB; reused as attention output
    bf16_t* wqkvb = (bf16_t*)(ws + 16 * MB);   // 6 MB   [3072][1024]
    bf16_t* wob   = (bf16_t*)(ws + 22 * MB);   // 2 MB
    bf16_t* QKV   = (bf16_t*)(ws + 24 * MB);   // 48 MB  [8192][3072]
    float*  conn  = (float*)(ws + 72 * MB);    // 448 B

    (void)hipFuncSetAttribute((const void*)gemm_fp<256, 128, DQKV, false, false>,
                              hipFuncAttributeMaxDynamicSharedMemorySize, 73728);
    (void)hipFuncSetAttribute((const void*)gemm_fp<128, 128, DM, true, true>,
                              hipFuncAttributeMaxDynamicSharedMemorySize, 49152);

    // casts + conn in one launch
    fused_cast_kernel<<<6160, 256, 0, stream>>>(x, wq, wk, wv, wo,
                                                cw1, cb1, cw2, cb2, cw3, cb3,
                                                xb, wqkvb, wob, conn);

    // QKV: 32 M-tiles x 24 N-tiles = 768 blocks (2 blocks/CU)
    gemm_fp<256, 128, DQKV, false, false><<<768, 512, 73728, stream>>>(xb, wqkvb, QKV, nullptr);

    // attention: 1024 blocks, LDS-staged K/V
    attn_win_kernel<<<NB * NH * (L_SEQ / LCH), 256, 0, stream>>>(QKV, conn, xb);

    // out-proj: 64 x 8 = 512 blocks
    gemm_fp<128, 128, DM, true, true><<<512, 512, 49152, stream>>>(xb, wob, out, bo);
}

// Round 11
// 118.582 us; speedup vs baseline: 1.0730x; 1.0527x over previous
//
#include <hip/hip_runtime.h>
#include <hip/hip_bf16.h>
#include <math.h>
#include <stdint.h>

#define L_SEQ 4096
#define NB 2
#define NH 16
#define DHEAD 64
#define DM 1024
#define DQKV 3072

typedef __bf16 bf16_t;
typedef __attribute__((ext_vector_type(8))) __bf16 bf16x8;
typedef __attribute__((ext_vector_type(4))) float f32x4;

#define GLD16(gp, lp) __builtin_amdgcn_global_load_lds(                          \
    (const __attribute__((address_space(1))) void*)(gp),                         \
    (__attribute__((address_space(3))) void*)(lp), 16, 0, 0)

template<int N> __device__ __forceinline__ void vmwait() {
    if constexpr (N == 3)      asm volatile("s_waitcnt vmcnt(3)" ::: "memory");
    else if constexpr (N == 2) asm volatile("s_waitcnt vmcnt(2)" ::: "memory");
    else                       asm volatile("s_waitcnt vmcnt(0)" ::: "memory");
}

// ---------------- fused fp32->bf16 casts + conn MLP ----------------
__device__ __forceinline__ void cast8(const float* src, bf16_t* dst)
{
    const f32x4* ip = (const f32x4*)src;
    f32x4 a = ip[0], b = ip[1];
    bf16x8 o;
    o[0] = (__bf16)a[0]; o[1] = (__bf16)a[1]; o[2] = (__bf16)a[2]; o[3] = (__bf16)a[3];
    o[4] = (__bf16)b[0]; o[5] = (__bf16)b[1]; o[6] = (__bf16)b[2]; o[7] = (__bf16)b[3];
    *(bf16x8*)dst = o;
}

__device__ __forceinline__ float gelu_exact(float z)
{
    return 0.5f * z * (1.0f + erff(z * 0.7071067811865475f));
}

// blocks 0..4095: x; 4096..5631: wq|wk|wv; 5632..6143: wo; 6144..6159: conn
__global__ __launch_bounds__(256) void fused_cast_kernel(
    const float* __restrict__ x,  const float* __restrict__ wq,
    const float* __restrict__ wk, const float* __restrict__ wv,
    const float* __restrict__ wo,
    const float* __restrict__ cw1, const float* __restrict__ cb1,
    const float* __restrict__ cw2, const float* __restrict__ cb2,
    const float* __restrict__ cw3, const float* __restrict__ cb3,
    bf16_t* __restrict__ xb, bf16_t* __restrict__ wqkvb, bf16_t* __restrict__ wob,
    float* __restrict__ conn)
{
    const int bid = blockIdx.x;
    const int tid = threadIdx.x;
    const int nW = DM * DM / 8;
    if (bid < 4096) {
        int t = bid * 256 + tid;
        cast8(x + (size_t)t * 8, xb + (size_t)t * 8);
    } else if (bid < 5632) {
        int t = (bid - 4096) * 256 + tid;
        const float* src; int lt;
        if (t < nW)          { src = wq; lt = t; }
        else if (t < 2 * nW) { src = wk; lt = t - nW; }
        else                 { src = wv; lt = t - 2 * nW; }
        cast8(src + (size_t)lt * 8, wqkvb + (size_t)t * 8);
    } else if (bid < 6144) {
        int t = (bid - 5632) * 256 + tid;
        cast8(wo + (size_t)t * 8, wob + (size_t)t * 8);
    } else {
        __shared__ float h1[7][32];
        __shared__ float h2[7][32];
        const int h = bid - 6144;
        const int j = tid;
        if (j < 32) {
            for (int w = 0; w < 7; ++w) {
                float pos = (float)w / 6.0f;
                float z = pos * cw1[h * 32 + j] + cb1[h * 32 + j];
                h1[w][j] = gelu_exact(z);
            }
        }
        __syncthreads();
        if (j < 32) {
            for (int w = 0; w < 7; ++w) {
                float z = cb2[h * 32 + j];
                for (int i = 0; i < 32; ++i) z += h1[w][i] * cw2[((size_t)h * 32 + j) * 32 + i];
                h2[w][j] = gelu_exact(z);
            }
        }
        __syncthreads();
        if (j == 0) {
            float cwt[7];
            float mx = -1e30f;
            for (int w = 0; w < 7; ++w) {
                float z = cb3[h];
                for (int i = 0; i < 32; ++i) z += h2[w][i] * cw3[h * 32 + i];
                cwt[w] = z;
                mx = fmaxf(mx, z);
            }
            float Z = 0.0f;
            for (int w = 0; w < 7; ++w) { cwt[w] = expf(cwt[w] - mx); Z += cwt[w]; }
            for (int w = 0; w < 7; ++w) conn[h * 7 + w] = cwt[w] / Z;
        }
    }
}

// ---------------- BMxBN bf16 GEMM, BK=32, triple-buffer (R8-proven, 16x16x32) ----------------
// C[M=8192, NOUT] = A @ Bw^T (+bias).  512 thr = 8 waves as 4M x 2N.
// Per K-tile t: vmcnt(L) -> s_barrier -> 8 ds_read_b128 -> stage tile t+2 ->
// setprio(1) 16 MFMA setprio(0).  Swizzle: dest 16B slot sd holds source slot
// sd^((row>>1)&3); reads use slot^((row>>1)&3) => 2-way banks (0 conflicts measured).
template<int BM, int BN, int NOUT, bool F32OUT, bool BIAS>
__global__ __launch_bounds__(512, 4) void gemm_fp(const bf16_t* __restrict__ A,
                                                  const bf16_t* __restrict__ Bw,
                                                  void* __restrict__ Cout,
                                                  const float* __restrict__ bias)
{
    constexpr int K   = 1024;
    constexpr int NT  = K / 32;
    constexpr int MI  = BM / 64;
    constexpr int NJ  = BN / 32;
    constexpr int LA  = BM / 128;
    constexpr int LB  = BN / 128;
    constexpr int L   = LA + LB;
    constexpr int ASZ = BM * 64;
    constexpr int BSZ = BN * 64;
    constexpr int NTN = NOUT / BN;

    extern __shared__ char smem[];

    const int tid  = threadIdx.x;
    const int lane = tid & 63;
    const int wave = tid >> 6;
    const int wm   = (wave >> 1) * (BM / 4);
    const int wn   = (wave & 1) * (BN / 2);

    const int nwg = gridDim.x;
    int id = blockIdx.x;
    id = (id & 7) * (nwg >> 3) + (id >> 3);
    const int bm = (id / NTN) * BM;
    const int bn = (id % NTN) * BN;

    const int scol = (((tid & 3) ^ ((tid >> 3) & 3)) * 8);
    const int srow = tid >> 2;
    const bf16_t* Ag = A  + (size_t)(bm + srow) * K + scol;
    const bf16_t* Bg = Bw + (size_t)(bn + srow) * K + scol;

    auto stage = [&](int kt) {
        char* la = smem + (kt % 3) * ASZ + tid * 16;
#pragma unroll
        for (int bl = 0; bl < LA; ++bl)
            GLD16(Ag + (size_t)(bl * 128) * K + kt * 32, la + bl * 8192);
        char* lb = smem + 3 * ASZ + (kt % 3) * BSZ + tid * 16;
#pragma unroll
        for (int bl = 0; bl < LB; ++bl)
            GLD16(Bg + (size_t)(bl * 128) * K + kt * 32, lb + bl * 8192);
    };

    f32x4 acc[MI][NJ] = {};

    stage(0); stage(1);

    int aoff[MI], boff[NJ];
#pragma unroll
    for (int m = 0; m < MI; ++m) {
        const int r = wm + m * 16 + (lane & 15);
        aoff[m] = r * 64 + (((lane >> 4) ^ ((r >> 1) & 3)) * 16);
    }
#pragma unroll
    for (int n = 0; n < NJ; ++n) {
        const int r = wn + n * 16 + (lane & 15);
        boff[n] = r * 64 + (((lane >> 4) ^ ((r >> 1) & 3)) * 16);
    }

    for (int t = 0; t < NT; ++t) {
        if (t < NT - 1) vmwait<L>(); else vmwait<0>();
        __builtin_amdgcn_s_barrier();
        asm volatile("" ::: "memory");

        const char* Ab = smem + (t % 3) * ASZ;
        const char* Bb = smem + 3 * ASZ + (t % 3) * BSZ;

        bf16x8 af[MI], bfr[NJ];
#pragma unroll
        for (int m = 0; m < MI; ++m) af[m]  = *(const bf16x8*)(Ab + aoff[m]);
#pragma unroll
        for (int n = 0; n < NJ; ++n) bfr[n] = *(const bf16x8*)(Bb + boff[n]);

        if (t + 2 < NT) {
            __builtin_amdgcn_sched_barrier(0);
            stage(t + 2);
        }

        __builtin_amdgcn_s_setprio(1);
#pragma unroll
        for (int m = 0; m < MI; ++m)
#pragma unroll
            for (int n = 0; n < NJ; ++n)
                acc[m][n] = __builtin_amdgcn_mfma_f32_16x16x32_bf16(af[m], bfr[n], acc[m][n], 0, 0, 0);
        __builtin_amdgcn_s_setprio(0);
    }

    const int r0 = (lane >> 4) * 4;
    const int c0 = lane & 15;
#pragma unroll
    for (int m = 0; m < MI; ++m) {
#pragma unroll
        for (int n = 0; n < NJ; ++n) {
            const int col = bn + wn + n * 16 + c0;
            float bv = BIAS ? bias[col] : 0.0f;
#pragma unroll
            for (int r = 0; r < 4; ++r) {
                const int row = bm + wm + m * 16 + r0 + r;
                float v = acc[m][n][r] + bv;
                if (F32OUT) ((float*)Cout)[(size_t)row * NOUT + col] = v;
                else        ((bf16_t*)Cout)[(size_t)row * NOUT + col] = (__bf16)v;
            }
        }
    }
}

// ---------------- windowed attention, LDS-staged K/V (R8-proven) ----------------
#define LCH 128
#define KROWS (LCH + 7)
#define RSTR 72

__global__ __launch_bounds__(256) void attn_win_kernel(const bf16_t* __restrict__ QKV,
                                                       const float* __restrict__ conn,
                                                       bf16_t* __restrict__ AO)
{
    __shared__ bf16_t Kl[KROWS * RSTR];
    __shared__ bf16_t Vl[KROWS * RSTR];

    const int tid = threadIdx.x;
    const int blk = blockIdx.x;
    const int lc  = blk & 31;
    const int h   = (blk >> 5) & (NH - 1);
    const int b   = blk >> 9;
    const int l0  = lc * LCH;
    const size_t baseK = (size_t)b * L_SEQ * DQKV + DM + h * DHEAD;
    const size_t baseV = baseK + DM;

#pragma unroll
    for (int it = 0; it < 5; ++it) {
        const int idx = it * 256 + tid;
        if (idx >= KROWS * 8) break;
        const int row = idx >> 3, c = idx & 7;
        const int l = l0 - 3 + row;
        bf16x8 kv = {}, vv = {};
        if ((unsigned)l < L_SEQ) {
            kv = *(const bf16x8*)(QKV + baseK + (size_t)l * DQKV + c * 8);
            vv = *(const bf16x8*)(QKV + baseV + (size_t)l * DQKV + c * 8);
        }
        *(bf16x8*)(Kl + row * RSTR + c * 8) = kv;
        *(bf16x8*)(Vl + row * RSTR + c * 8) = vv;
    }
    __syncthreads();

    const int ll = tid >> 3;
    const int c  = tid & 7;

#pragma unroll
    for (int q = 0; q < LCH / 32; ++q) {
        const int lrow = ll + q * 32;
        const int l    = l0 + lrow;
        const size_t row = (size_t)b * L_SEQ + l;

        const bf16x8 qv = *(const bf16x8*)(QKV + row * DQKV + h * DHEAD + c * 8);

        float s[7];
#pragma unroll
        for (int o = 0; o < 7; ++o) {
            const bf16x8 kv = *(const bf16x8*)(Kl + (lrow + o) * RSTR + c * 8);
            float d = 0.0f;
#pragma unroll
            for (int j = 0; j < 8; ++j) d += (float)qv[j] * (float)kv[j];
            s[o] = d;
        }
#pragma unroll
        for (int m = 1; m < 8; m <<= 1) {
#pragma unroll
            for (int o = 0; o < 7; ++o) s[o] += __shfl_xor(s[o], m, 64);
        }

        float mx = -1e30f;
#pragma unroll
        for (int o = 0; o < 7; ++o) { s[o] *= 0.125f; mx = fmaxf(mx, s[o]); }
        float e[7], Z = 0.0f;
#pragma unroll
        for (int o = 0; o < 7; ++o) { e[o] = expf(s[o] - mx); Z += e[o]; }

        float fw[7], fs = 0.0f;
#pragma unroll
        for (int o = 0; o < 7; ++o) { fw[o] = e[o] * conn[h * 7 + o]; fs += fw[o]; }
        const float inv = 1.0f / (fs + 1e-9f * Z);

        float outv[8] = {};
#pragma unroll
        for (int o = 0; o < 7; ++o) {
            const float w = fw[o] * inv;
            const bf16x8 vv = *(const bf16x8*)(Vl + (lrow + o) * RSTR + c * 8);
#pragma unroll
            for (int j = 0; j < 8; ++j) outv[j] += w * (float)vv[j];
        }

        bf16x8 ov;
#pragma unroll
        for (int j = 0; j < 8; ++j) ov[j] = (__bf16)outv[j];
        *(bf16x8*)(AO + row * DM + h * DHEAD + c * 8) = ov;
    }
}

// ---------------- launch ----------------
extern "C" void kernel_launch(void* const* d_in, const int* in_sizes, int n_in,
                              void* d_out, int out_size, void* d_ws, size_t ws_size,
                              hipStream_t stream)
{
    const float* x   = (const float*)d_in[0];
    const float* wq  = (const float*)d_in[1];
    const float* wk  = (const float*)d_in[2];
    const float* wv  = (const float*)d_in[3];
    const float* wo  = (const float*)d_in[4];
    const float* bo  = (const float*)d_in[5];
    const float* cw1 = (const float*)d_in[6];
    const float* cb1 = (const float*)d_in[7];
    const float* cw2 = (const float*)d_in[8];
    const float* cb2 = (const float*)d_in[9];
    const float* cw3 = (const float*)d_in[10];
    const float* cb3 = (const float*)d_in[11];
    float* out = (float*)d_out;

    char* ws = (char*)d_ws;
    const size_t MB = 1024 * 1024;
    bf16_t* xb    = (bf16_t*)(ws);             // 16 MB; reused as attention output
    bf16_t* wqkvb = (bf16_t*)(ws + 16 * MB);   // 6 MB   [3072][1024]
    bf16_t* wob   = (bf16_t*)(ws + 22 * MB);   // 2 MB
    bf16_t* QKV   = (bf16_t*)(ws + 24 * MB);   // 48 MB  [8192][3072]
    float*  conn  = (float*)(ws + 72 * MB);    // 448 B

    (void)hipFuncSetAttribute((const void*)gemm_fp<256, 128, DQKV, false, false>,
                              hipFuncAttributeMaxDynamicSharedMemorySize, 73728);
    (void)hipFuncSetAttribute((const void*)gemm_fp<256, 128, DM, true, true>,
                              hipFuncAttributeMaxDynamicSharedMemorySize, 73728);

    // casts + conn in one launch
    fused_cast_kernel<<<6160, 256, 0, stream>>>(x, wq, wk, wv, wo,
                                                cw1, cb1, cw2, cb2, cw3, cb3,
                                                xb, wqkvb, wob, conn);

    // QKV: 32 M-tiles x 24 N-tiles = 768 blocks (2 blocks/CU)
    gemm_fp<256, 128, DQKV, false, false><<<768, 512, 73728, stream>>>(xb, wqkvb, QKV, nullptr);

    // attention: 1024 blocks, LDS-staged K/V
    attn_win_kernel<<<NB * NH * (L_SEQ / LCH), 256, 0, stream>>>(QKV, conn, xb);

    // out-proj: 32 x 8 = 256 blocks, same proven 256x128 shape (16 MFMA/barrier)
    gemm_fp<256, 128, DM, true, true><<<256, 512, 73728, stream>>>(xb, wob, out, bo);
}